// Round 1
// baseline (983.669 us; speedup 1.0000x reference)
//
#include <hip/hip_runtime.h>
#include <stdint.h>

#define T_TOK 2048
#define NEXP  32
#define HID   2048
#define INTER 1024

typedef unsigned short u16;
typedef unsigned int   u32;
typedef __bf16 bf16x8 __attribute__((ext_vector_type(8)));
typedef __bf16 bf16x2 __attribute__((ext_vector_type(2)));
typedef float  f32x4  __attribute__((ext_vector_type(4)));

// Native bf16 conversion: compiler emits v_cvt_pk_bf16_f32 (RNE) on gfx950.
// (Hand-rolled integer RNE was ~5 VALU ops/elem and dominated staging time.)
__device__ __forceinline__ u16 f2bf(float f) {
  union { __bf16 b; u16 u; } c; c.b = (__bf16)f; return c.u;
}
__device__ __forceinline__ u32 packbf(float lo, float hi) {
  union { bf16x2 v; u32 u; } c;
  c.v[0] = (__bf16)lo; c.v[1] = (__bf16)hi;
  return c.u;
}

// ---------------- router: one block per token ----------------
__global__ __launch_bounds__(256) void router_kernel(
    const float* __restrict__ x, const float* __restrict__ rw,
    const float* __restrict__ bias, int* __restrict__ topk_idx,
    float* __restrict__ topk_w, int* __restrict__ counts) {
  __shared__ float xs[HID];
  __shared__ float part[8][33];
  __shared__ float sc[32], sb[32];
  const int t = blockIdx.x;
  const int tid = threadIdx.x;

  const float4* xv = (const float4*)(x + (size_t)t * HID);
  float4* xsv = (float4*)xs;
  xsv[tid] = xv[tid];
  xsv[tid + 256] = xv[tid + 256];
  __syncthreads();

  const int e = tid & 31, c = tid >> 5;
  const float4* wv = (const float4*)(rw + (size_t)e * HID + c * 256);
  const float4* xc = (const float4*)(xs + c * 256);
  float p = 0.f;
#pragma unroll 8
  for (int i = 0; i < 64; ++i) {
    float4 a = xc[i], b = wv[i];
    p += a.x * b.x + a.y * b.y + a.z * b.z + a.w * b.w;
  }
  part[c][e] = p;
  __syncthreads();

  if (tid < 32) {
    float l = 0.f;
#pragma unroll
    for (int i = 0; i < 8; ++i) l += part[i][tid];
    float s = 1.f / (1.f + __expf(-l));
    sc[tid] = s;
    sb[tid] = s + bias[tid];
  }
  __syncthreads();

  if (tid == 0) {
    unsigned chosen = 0;
    int idxs[4]; float wk[4]; float sum = 0.f;
#pragma unroll
    for (int k = 0; k < 4; ++k) {
      float best = -1e30f; int bi = 0;
      for (int j = 0; j < 32; ++j)
        if (!((chosen >> j) & 1u) && sb[j] > best) { best = sb[j]; bi = j; }
      chosen |= 1u << bi; idxs[k] = bi; wk[k] = sc[bi]; sum += sc[bi];
    }
    float inv = 1.f / (sum + 1e-20f);
    for (int k = 0; k < 4; ++k) {
      topk_idx[t * 4 + k] = idxs[k];
      topk_w[t * 4 + k] = wk[k] * inv;
      atomicAdd(&counts[idxs[k]], 1);
    }
  }
}

// ---------------- prefix over expert counts ----------------
__global__ void prefix_kernel(const int* __restrict__ counts, int* __restrict__ offsets) {
  if (threadIdx.x == 0) {
    int acc = 0;
    for (int e = 0; e < NEXP; ++e) { offsets[e] = acc; acc += counts[e]; }
    offsets[NEXP] = acc;  // total routed slots (= T*K); base for shared-expert h rows
  }
}

// ---------------- scatter tokens into expert buckets ----------------
__global__ __launch_bounds__(256) void scatter_kernel(
    const int* __restrict__ topk_idx, const float* __restrict__ topk_w,
    const int* __restrict__ offsets, int* __restrict__ fill,
    int* __restrict__ rows, float* __restrict__ rweight) {
  int t = blockIdx.x * 256 + threadIdx.x;
  if (t >= T_TOK) return;
#pragma unroll
  for (int k = 0; k < 4; ++k) {
    int e = topk_idx[t * 4 + k];
    int slot = atomicAdd(&fill[e], 1);
    int p = offsets[e] + slot;
    rows[p] = t;
    rweight[p] = topk_w[t * 4 + k];
  }
}

// ---------------- x -> bf16 pre-conversion (once per launch) ----------------
// Removes the 16x redundant fp32->bf16 of x in pass1 (once per nt-tile) and
// halves A-side L2 bytes. Each thread: 8 floats -> 4 packed u32 (4 cvt_pk).
__global__ __launch_bounds__(256) void xconv_kernel(
    const float* __restrict__ x, u16* __restrict__ xbf) {
  int i = blockIdx.x * 256 + threadIdx.x;           // i indexes groups of 8 elems
  const float4* xv = (const float4*)x;
  float4 a = xv[i * 2], b = xv[i * 2 + 1];
  uint4 o = uint4(packbf(a.x, a.y), packbf(a.z, a.w),
                  packbf(b.x, b.y), packbf(b.z, b.w));
  ((uint4*)xbf)[i] = o;
}

// ---------------- pass1: h = silu(x@wg) * (x@wu)  (gathered, MFMA bf16) ----------------
// grid: x = INTER/64 (16), y = m-tiles (16), z = expert (33; 32 == shared)
__global__ __launch_bounds__(256, 2) void pass1_kernel(
    const u16* __restrict__ xbf,
    const float* __restrict__ w_gate, const float* __restrict__ w_up,
    const float* __restrict__ sw_gate, const float* __restrict__ sw_up,
    const int* __restrict__ counts, const int* __restrict__ offsets,
    const int* __restrict__ rows, u16* __restrict__ hbuf) {
  const int nt = blockIdx.x;
  const int mt = blockIdx.y;
  const int e  = blockIdx.z;

  const int cnt  = (e < NEXP) ? counts[e] : T_TOK;
  if (mt * 128 >= cnt) return;
  const int base = offsets[e];
  const float* wg = (e < NEXP) ? (w_gate + (size_t)e * HID * INTER) : sw_gate;
  const float* wu = (e < NEXP) ? (w_up   + (size_t)e * HID * INTER) : sw_up;

  __shared__ u16 As[128][72];      // [m][k] bf16, row stride 144B (16B-aligned, bank-spread)
  __shared__ u32 Bg[64][36];       // [n][k-pair] packed bf16x2
  __shared__ u32 Bu[64][36];

  const int tid = threadIdx.x;
  // A staging: 2 threads per row, 32 k-elements each
  const int arow = tid >> 1, ahalf = tid & 1;
  const int gm_a = mt * 128 + arow;
  int tok;
  if (e < NEXP) {
    int p = base + gm_a; if (p > T_TOK * 4 - 1) p = T_TOK * 4 - 1;
    tok = rows[p];                 // rows[] fully populated (sum counts == T*K)
  } else {
    tok = gm_a;                    // shared expert: identity mapping (gm_a < 2048)
  }
  const u16* xrow = xbf + (size_t)tok * HID + ahalf * 32;

  // B staging: nq = col-quad (coalesced), kph = k-pair
  const int nq = tid & 15, kph = tid >> 4;

  const int wave = tid >> 6, lane = tid & 63, q = lane >> 4, r = lane & 15;

  f32x4 accg[2][4], accu[2][4];
#pragma unroll
  for (int s = 0; s < 2; ++s)
#pragma unroll
    for (int ns = 0; ns < 4; ++ns) { accg[s][ns] = (f32x4)0.f; accu[s][ns] = (f32x4)0.f; }

  for (int kk = 0; kk < HID; kk += 64) {
    __syncthreads();
    // ---- stage A (already bf16: pure 64B copy) ----
    {
      const uint4* xv = (const uint4*)(xrow + kk);
      uint4 v0 = xv[0], v1 = xv[1], v2 = xv[2], v3 = xv[3];
      uint4* dst = (uint4*)&As[arow][ahalf * 32];
      dst[0] = v0; dst[1] = v1; dst[2] = v2; dst[3] = v3;
    }
    // ---- stage Bg/Bu with pair-pack transpose (native cvt_pk) ----
#pragma unroll
    for (int it = 0; it < 2; ++it) {
      const int kp = kph + it * 16;
      const size_t goff = (size_t)(kk + 2 * kp) * INTER + nt * 64 + nq * 4;
      float4 a0 = *(const float4*)(wg + goff);
      float4 a1 = *(const float4*)(wg + goff + INTER);
      float4 b0 = *(const float4*)(wu + goff);
      float4 b1 = *(const float4*)(wu + goff + INTER);
      u32 pg[4] = {packbf(a0.x, a1.x), packbf(a0.y, a1.y), packbf(a0.z, a1.z), packbf(a0.w, a1.w)};
      u32 pu[4] = {packbf(b0.x, b1.x), packbf(b0.y, b1.y), packbf(b0.z, b1.z), packbf(b0.w, b1.w)};
#pragma unroll
      for (int j = 0; j < 4; ++j) {
        int i = (j + nq) & 3;     // rotate to spread LDS banks
        Bg[nq * 4 + i][kp] = pg[i];
        Bu[nq * 4 + i][kp] = pu[i];
      }
    }
    __syncthreads();
    // ---- compute ----
#pragma unroll
    for (int ks = 0; ks < 64; ks += 32) {
      bf16x8 af0 = *(const bf16x8*)&As[wave * 32 + r][ks + q * 8];
      bf16x8 af1 = *(const bf16x8*)&As[wave * 32 + 16 + r][ks + q * 8];
#pragma unroll
      for (int ns = 0; ns < 4; ++ns) {
        bf16x8 bg = *(const bf16x8*)&Bg[ns * 16 + r][(ks >> 1) + q * 4];
        bf16x8 bu = *(const bf16x8*)&Bu[ns * 16 + r][(ks >> 1) + q * 4];
        accg[0][ns] = __builtin_amdgcn_mfma_f32_16x16x32_bf16(af0, bg, accg[0][ns], 0, 0, 0);
        accg[1][ns] = __builtin_amdgcn_mfma_f32_16x16x32_bf16(af1, bg, accg[1][ns], 0, 0, 0);
        accu[0][ns] = __builtin_amdgcn_mfma_f32_16x16x32_bf16(af0, bu, accu[0][ns], 0, 0, 0);
        accu[1][ns] = __builtin_amdgcn_mfma_f32_16x16x32_bf16(af1, bu, accu[1][ns], 0, 0, 0);
      }
    }
  }

  // ---- epilogue: silu(g)*u -> bf16 h ----
#pragma unroll
  for (int s = 0; s < 2; ++s) {
#pragma unroll
    for (int j = 0; j < 4; ++j) {
      int gm = mt * 128 + wave * 32 + s * 16 + q * 4 + j;  // D row = q*4 + reg
      if (gm < cnt) {
        size_t hoff = (size_t)(base + gm) * INTER + nt * 64;
#pragma unroll
        for (int ns = 0; ns < 4; ++ns) {
          float g = accg[s][ns][j], u = accu[s][ns][j];
          float hv = g / (1.f + __expf(-g)) * u;
          hbuf[hoff + ns * 16 + r] = f2bf(hv);             // D col = lane&15
        }
      }
    }
  }
}

// ---------------- pass2: out += (h @ wd) * weight ----------------
// grid: x = HID/64 (32), y = m-tiles (16), z = expert (33)
__global__ __launch_bounds__(256, 2) void pass2_kernel(
    const u16* __restrict__ hbuf,
    const float* __restrict__ w_down, const float* __restrict__ sw_down,
    const int* __restrict__ counts, const int* __restrict__ offsets,
    const int* __restrict__ rows, const float* __restrict__ rweight,
    float* __restrict__ out) {
  const int nt = blockIdx.x;
  const int mt = blockIdx.y;
  const int e  = blockIdx.z;

  const int cnt  = (e < NEXP) ? counts[e] : T_TOK;
  if (mt * 128 >= cnt) return;
  const int base = offsets[e];
  const float* wd = (e < NEXP) ? (w_down + (size_t)e * INTER * HID) : sw_down;

  __shared__ u16 As[128][72];
  __shared__ u32 Bd[64][36];

  const int tid = threadIdx.x;
  const int arow = tid >> 1, ahalf = tid & 1;
  const u16* hrow = hbuf + (size_t)(base + mt * 128 + arow) * INTER + ahalf * 32;
  const int nq = tid & 15, kph = tid >> 4;
  const int wave = tid >> 6, lane = tid & 63, q = lane >> 4, r = lane & 15;

  f32x4 acc[2][4];
#pragma unroll
  for (int s = 0; s < 2; ++s)
#pragma unroll
    for (int ns = 0; ns < 4; ++ns) acc[s][ns] = (f32x4)0.f;

  for (int kk = 0; kk < INTER; kk += 64) {
    __syncthreads();
    // ---- stage A (h already bf16) ----
    {
      const uint4* hv = (const uint4*)(hrow + kk);
      uint4 h0 = hv[0], h1 = hv[1], h2 = hv[2], h3 = hv[3];
      uint4* dst = (uint4*)&As[arow][ahalf * 32];
      dst[0] = h0; dst[1] = h1; dst[2] = h2; dst[3] = h3;
    }
    // ---- stage Bd (native cvt_pk) ----
#pragma unroll
    for (int it = 0; it < 2; ++it) {
      const int kp = kph + it * 16;
      const size_t goff = (size_t)(kk + 2 * kp) * HID + nt * 64 + nq * 4;
      float4 a0 = *(const float4*)(wd + goff);
      float4 a1 = *(const float4*)(wd + goff + HID);
      u32 pd[4] = {packbf(a0.x, a1.x), packbf(a0.y, a1.y), packbf(a0.z, a1.z), packbf(a0.w, a1.w)};
#pragma unroll
      for (int j = 0; j < 4; ++j) {
        int i = (j + nq) & 3;
        Bd[nq * 4 + i][kp] = pd[i];
      }
    }
    __syncthreads();
#pragma unroll
    for (int ks = 0; ks < 64; ks += 32) {
      bf16x8 af0 = *(const bf16x8*)&As[wave * 32 + r][ks + q * 8];
      bf16x8 af1 = *(const bf16x8*)&As[wave * 32 + 16 + r][ks + q * 8];
#pragma unroll
      for (int ns = 0; ns < 4; ++ns) {
        bf16x8 bd = *(const bf16x8*)&Bd[ns * 16 + r][(ks >> 1) + q * 4];
        acc[0][ns] = __builtin_amdgcn_mfma_f32_16x16x32_bf16(af0, bd, acc[0][ns], 0, 0, 0);
        acc[1][ns] = __builtin_amdgcn_mfma_f32_16x16x32_bf16(af1, bd, acc[1][ns], 0, 0, 0);
      }
    }
  }

  // ---- epilogue: weighted atomic accumulate into out ----
#pragma unroll
  for (int s = 0; s < 2; ++s) {
#pragma unroll
    for (int j = 0; j < 4; ++j) {
      int gm = mt * 128 + wave * 32 + s * 16 + q * 4 + j;
      if (gm < cnt) {
        int token; float wgt;
        if (e < NEXP) { int gi = base + gm; token = rows[gi]; wgt = rweight[gi]; }
        else          { token = gm; wgt = 1.f; }
        float* orow = out + (size_t)token * HID + nt * 64;
#pragma unroll
        for (int ns = 0; ns < 4; ++ns)
          atomicAdd(&orow[ns * 16 + r], acc[s][ns][j] * wgt);
      }
    }
  }
}

extern "C" void kernel_launch(void* const* d_in, const int* in_sizes, int n_in,
                              void* d_out, int out_size, void* d_ws, size_t ws_size,
                              hipStream_t stream) {
  const float* x       = (const float*)d_in[0];
  const float* rw      = (const float*)d_in[1];
  const float* bias    = (const float*)d_in[2];
  const float* w_gate  = (const float*)d_in[3];
  const float* w_up    = (const float*)d_in[4];
  const float* w_down  = (const float*)d_in[5];
  const float* sw_gate = (const float*)d_in[6];
  const float* sw_up   = (const float*)d_in[7];
  const float* sw_down = (const float*)d_in[8];
  float* out = (float*)d_out;

  char* ws = (char*)d_ws;
  int*   counts   = (int*)(ws + 0);        // 33 ints
  int*   offsets  = (int*)(ws + 256);      // 33 ints
  int*   fill     = (int*)(ws + 512);      // 32 ints
  int*   topk_idx = (int*)(ws + 1024);     // 8192 ints
  float* topk_w   = (float*)(ws + 33792);  // 8192 floats
  int*   rows     = (int*)(ws + 66560);    // 8192 ints
  float* rweight  = (float*)(ws + 99328);  // 8192 floats
  u16*   hbuf     = (u16*)(ws + 132096);   // 10240 * 1024 bf16 = 20.97 MB
  u16*   xbf      = (u16*)(ws + 132096 + (size_t)10240 * 1024 * 2);  // 2048*2048 bf16 = 8.4 MB

  hipMemsetAsync(d_out, 0, (size_t)out_size * sizeof(float), stream);
  hipMemsetAsync(ws, 0, 1024, stream);

  router_kernel<<<T_TOK, 256, 0, stream>>>(x, rw, bias, topk_idx, topk_w, counts);
  xconv_kernel<<<T_TOK * HID / 8 / 256, 256, 0, stream>>>(x, xbf);
  prefix_kernel<<<1, 64, 0, stream>>>(counts, offsets);
  scatter_kernel<<<8, 256, 0, stream>>>(topk_idx, topk_w, offsets, fill, rows, rweight);
  pass1_kernel<<<dim3(16, 16, 33), 256, 0, stream>>>(
      xbf, w_gate, w_up, sw_gate, sw_up, counts, offsets, rows, hbuf);
  pass2_kernel<<<dim3(32, 16, 33), 256, 0, stream>>>(
      hbuf, w_down, sw_down, counts, offsets, rows, rweight, out);
}